// Round 4
// baseline (311.740 us; speedup 1.0000x reference)
//
#include <hip/hip_runtime.h>
#include <hip/hip_bf16.h>

#define BATCH 8
#define NDIM  2048
#define MDIM  2048
#define CDIM  128

typedef __attribute__((ext_vector_type(8))) short bf16x8;
typedef __attribute__((ext_vector_type(4))) float f32x4;

__device__ __forceinline__ float bf2f(unsigned int u16){
    union { unsigned int u; float f; } v; v.u = u16 << 16; return v.f;
}
__device__ __forceinline__ unsigned int f2bf(float f){
    union { float f; unsigned int u; } v; v.f = f;
    unsigned int u = v.u;
    u += 0x7FFFu + ((u >> 16) & 1u);   // round-to-nearest-even
    return u >> 16;
}

// ws layout: float partial sums [0..31], int partial counts at dwords [32..63]
__global__ void ws_init_kernel(unsigned int* wsu){
    wsu[threadIdx.x] = 0u;     // 64 threads zero 64 dwords
}

__global__ void finalize_kernel(const float* wsf, float* out){
    float s = 0.f;
    int   c = 0;
    #pragma unroll
    for (int i = 0; i < 32; ++i){
        s += wsf[i];
        c += ((const int*)wsf)[32 + i];
    }
    out[0] = s / (float)c;
}

// launch_bounds(256,4): 128-reg unified cap (64 VGPR + 64 AGPR acc, measured R3).
// (256,5) capped at 102 and SPILLED the accumulator (R2: FETCH +229MB, dur 401us).
__global__ __launch_bounds__(256, 4) void cossim_bce_main(
    const int*  __restrict__ zp,
    const float* __restrict__ x1,
    const float* __restrict__ x2,
    const float* __restrict__ tparm,
    const float* __restrict__ bparm,
    float* __restrict__ out,
    float* __restrict__ wsf)
{
    // 32 KB LDS total.
    // lA/lB: 128x64 bf16 K-phase tiles (16 KB each), XOR-swizzled.
    // After GEMM: lA reused for norms (1 KB), lB reused for 32x128 f32 cos strip (16 KB).
    __shared__ __align__(16) unsigned short lA[128*64];
    __shared__ __align__(16) unsigned short lB[128*64];

    const int t  = threadIdx.x;
    const int bx = blockIdx.x;   // M tile
    const int by = blockIdx.y;   // N tile
    const int bz = blockIdx.z;   // batch

    const float tv = *tparm;
    const float bv = *bparm;

    const float* x1base = x1 + ((size_t)(bz*NDIM) + by*128) * CDIM;
    const float* x2base = x2 + ((size_t)(bz*MDIM) + bx*128) * CDIM;

    const int lane = t & 63;
    const int w    = t >> 6;
    const int wrow = (w >> 1) * 64;  // wave output row offset
    const int wcol = (w & 1) * 64;   // wave output col offset
    const int quad = lane >> 4;      // 0..3
    const int l16  = lane & 15;

    f32x4 acc[4][4];
    #pragma unroll
    for (int m = 0; m < 4; ++m)
        #pragma unroll
        for (int n = 0; n < 4; ++n)
            acc[m][n] = (f32x4){0.f, 0.f, 0.f, 0.f};

    float nsum = 0.f;                // per-thread norm partial (row t&127 of A or B)
    const int nrow = t & 127;

    // ---- two K-phases of 64 ----
    #pragma unroll
    for (int ph = 0; ph < 2; ++ph){
        // stage: f32 -> bf16, swizzled LDS writes (chunk ^ row&7)
        #pragma unroll
        for (int i = 0; i < 4; ++i){
            int chunk = i*256 + t;       // 1024 16B-chunks per tile
            int row = chunk >> 3;        // 0..127
            int pos = chunk & 7;         // 16B chunk within 64-col row
            int sw  = pos ^ (row & 7);
            {
                const float* p = x1base + row*CDIM + ph*64 + pos*8;
                float4 a = *(const float4*)p;
                float4 b = *(const float4*)(p + 4);
                uint4 pk;
                pk.x = f2bf(a.x) | (f2bf(a.y) << 16);
                pk.y = f2bf(a.z) | (f2bf(a.w) << 16);
                pk.z = f2bf(b.x) | (f2bf(b.y) << 16);
                pk.w = f2bf(b.z) | (f2bf(b.w) << 16);
                ((uint4*)lA)[row*8 + sw] = pk;
            }
            {
                const float* p = x2base + row*CDIM + ph*64 + pos*8;
                float4 a = *(const float4*)p;
                float4 b = *(const float4*)(p + 4);
                uint4 pk;
                pk.x = f2bf(a.x) | (f2bf(a.y) << 16);
                pk.y = f2bf(a.z) | (f2bf(a.w) << 16);
                pk.z = f2bf(b.x) | (f2bf(b.y) << 16);
                pk.w = f2bf(b.z) | (f2bf(b.w) << 16);
                ((uint4*)lB)[row*8 + sw] = pk;
            }
        }
        __syncthreads();

        // MFMA: 2 k-steps of 32 per phase
        #pragma unroll
        for (int kk = 0; kk < 2; ++kk){
            const int kc = kk*4 + quad;          // 16B k-chunk 0..7
            bf16x8 afr[4], bfr[4];
            #pragma unroll
            for (int m = 0; m < 4; ++m){
                int row = wrow + m*16 + l16;
                afr[m] = ((const bf16x8*)lA)[row*8 + (kc ^ (row & 7))];
            }
            #pragma unroll
            for (int n = 0; n < 4; ++n){
                int row = wcol + n*16 + l16;
                bfr[n] = ((const bf16x8*)lB)[row*8 + (kc ^ (row & 7))];
            }
            #pragma unroll
            for (int m = 0; m < 4; ++m)
                #pragma unroll
                for (int n = 0; n < 4; ++n)
                    acc[m][n] = __builtin_amdgcn_mfma_f32_16x16x32_bf16(
                                    afr[m], bfr[n], acc[m][n], 0, 0, 0);
        }

        // norm partials from the bf16 tiles (one row per thread)
        {
            const unsigned short* src = (t < 128) ? lA : lB;
            #pragma unroll
            for (int c = 0; c < 8; ++c){
                uint4 v = ((const uint4*)src)[nrow*8 + (c ^ (nrow & 7))];
                float f0 = bf2f(v.x & 0xffffu), f1 = bf2f(v.x >> 16);
                float f2 = bf2f(v.y & 0xffffu), f3 = bf2f(v.y >> 16);
                float f4 = bf2f(v.z & 0xffffu), f5 = bf2f(v.z >> 16);
                float f6 = bf2f(v.w & 0xffffu), f7 = bf2f(v.w >> 16);
                nsum += f0*f0 + f1*f1 + f2*f2 + f3*f3 + f4*f4 + f5*f5 + f6*f6 + f7*f7;
            }
        }
        __syncthreads();   // tile reads done before restage / nsh reuse
    }

    // ---- norms into LDS (reuse lA) ----
    float* nsh = (float*)lA;         // [0..127]=1/||x1 row||, [128..255]=1/||x2 row||
    nsh[t] = 1.0f / sqrtf(fmaxf(nsum, 1e-16f));
    __syncthreads();

    // ---- epilogue: 4 strips of 32 rows via LDS transpose (reuse lB) ----
    float* cosT = (float*)lB;        // [32][128] f32
    float* cosOut  = out + 1;
    float* maskOut = out + 1 + (size_t)BATCH*NDIM*MDIM;
    const size_t strideBase = (size_t)bz*NDIM*MDIM + (size_t)(by*128)*MDIM + (size_t)(bx*128);

    float lnum = 0.f;
    int   lcnt = 0;

    // prefetch z for strip 0 (latency hides under producer writes + barrier)
    int4 zpre[4];
    #pragma unroll
    for (int i = 0; i < 4; ++i){
        int f = i*256 + t;
        int rowRel = f >> 5;
        int c4 = f & 31;
        zpre[i] = *(const int4*)(zp + strideBase + (size_t)rowRel*MDIM + c4*4);
    }

    #pragma unroll
    for (int q = 0; q < 4; ++q){
        // producers: waves owning rows q*32 .. q*32+31
        if ((w >> 1) == (q >> 1)){
            #pragma unroll
            for (int mi = 0; mi < 2; ++mi){
                int m = (q & 1)*2 + mi;
                #pragma unroll
                for (int n = 0; n < 4; ++n){
                    int colL = wcol + n*16 + l16;
                    float in2 = nsh[128 + colL];
                    #pragma unroll
                    for (int r = 0; r < 4; ++r){
                        int rowRel = mi*16 + quad*4 + r;
                        float in1 = nsh[q*32 + rowRel];
                        cosT[rowRel*128 + colL] = acc[m][n][r] * in1 * in2;
                    }
                }
            }
        }
        __syncthreads();

        // all threads: streaming write-out of 32 rows x 128 cols.
        // Stores are re-aligned: thread c4 stores {prev.w, x, y, z} at out[rbase+4*c4]
        // (16B-aligned despite the +1 output offset); c4==0 writes the 3 head
        // scalars, c4==31 the tail scalar. All cached -> L2 merges full lines.
        #pragma unroll
        for (int i = 0; i < 4; ++i){
            int f = i*256 + t;           // float4 index 0..1023
            int rowRel = f >> 5;
            int c4 = f & 31;             // == lane & 31
            size_t rowIdx = strideBase + (size_t)(q*32 + rowRel)*MDIM;
            size_t idx = rowIdx + c4*4;

            int4 z4 = zpre[i];
            if (q < 3)                   // issue next strip's z load NOW
                zpre[i] = *(const int4*)(zp + idx + (size_t)32*MDIM);

            f32x4 cs4 = ((const f32x4*)cosT)[f];

            f32x4 mk;
            float nl = 0.f;
            int   nc = 0;
            #pragma unroll
            for (int j = 0; j < 4; ++j){
                int zv = (&z4.x)[j];
                float cs = cs4[j];
                mk[j] = zv ? 1.0f : 0.0f;
                float y  = (float)zv * (tv*cs - bv);
                float nll = fmaxf(-y, 0.f) + __logf(1.0f + __expf(-fabsf(y)));
                nl += zv ? nll : 0.f;
                nc += zv ? 1 : 0;
            }
            lnum += nl;
            lcnt += nc;

            float pcw = __shfl_up(cs4[3], 1);
            float pmw = __shfl_up(mk[3], 1);
            if (c4 != 0){
                f32x4 sc = {pcw, cs4[0], cs4[1], cs4[2]};
                f32x4 sm = {pmw, mk[0],  mk[1],  mk[2]};
                *(f32x4*)(cosOut  + idx - 1) = sc;   // byte addr = 4*(rowIdx+4*c4) -> aligned
                *(f32x4*)(maskOut + idx - 1) = sm;
            } else {
                cosOut[rowIdx] = cs4[0];
                *(float2*)(cosOut + rowIdx + 1) = make_float2(cs4[1], cs4[2]);
                maskOut[rowIdx] = mk[0];
                *(float2*)(maskOut + rowIdx + 1) = make_float2(mk[1], mk[2]);
            }
            if (c4 == 31){
                cosOut[rowIdx + 127]  = cs4[3];
                maskOut[rowIdx + 127] = mk[3];
            }
        }
        __syncthreads();      // before next strip overwrites cosT (and before reduce reuse)
    }

    // ---- block-level loss reduction: 1 atomic pair per block, 32 spread cells ----
    #pragma unroll
    for (int off = 32; off > 0; off >>= 1){
        lnum += __shfl_down(lnum, off);
        lcnt += __shfl_down(lcnt, off);
    }
    float* redf = (float*)lB;
    int*   redi = (int*)lB + 8;
    if (lane == 0){ redf[w] = lnum; redi[w] = lcnt; }
    __syncthreads();
    if (t == 0){
        float s = redf[0] + redf[1] + redf[2] + redf[3];
        int   c = redi[0] + redi[1] + redi[2] + redi[3];
        int cell = (bx + by*16 + bz*256) & 31;
        atomicAdd(wsf + cell, s);
        atomicAdd((int*)wsf + 32 + cell, c);
    }
}

extern "C" void kernel_launch(void* const* d_in, const int* in_sizes, int n_in,
                              void* d_out, int out_size, void* d_ws, size_t ws_size,
                              hipStream_t stream) {
    const int*   zp = (const int*)  d_in[0];
    const float* x1 = (const float*)d_in[1];
    const float* x2 = (const float*)d_in[2];
    const float* tp = (const float*)d_in[3];
    const float* bp = (const float*)d_in[4];
    float* out = (float*)d_out;
    float* wsf = (float*)d_ws;

    ws_init_kernel<<<1, 64, 0, stream>>>((unsigned int*)d_ws);
    dim3 grid(MDIM/128, NDIM/128, BATCH);
    cossim_bce_main<<<grid, 256, 0, stream>>>(zp, x1, x2, tp, bp, out, wsf);
    finalize_kernel<<<1, 1, 0, stream>>>(wsf, out);
}

// Round 5
// 169.688 us; speedup vs baseline: 1.8371x; 1.8371x over previous
//
#include <hip/hip_runtime.h>
#include <hip/hip_bf16.h>

#define BATCH 8
#define NDIM  2048
#define MDIM  2048
#define CDIM  128

typedef __attribute__((ext_vector_type(8))) short bf16x8;
typedef __attribute__((ext_vector_type(4))) float f32x4;
// 4B-aligned float4 for the (out+1)-offset misaligned global stores
typedef __attribute__((ext_vector_type(4), aligned(4))) float f32x4u;

__device__ __forceinline__ float bf2f(unsigned int u16){
    union { unsigned int u; float f; } v; v.u = u16 << 16; return v.f;
}
__device__ __forceinline__ unsigned int f2bf(float f){
    union { float f; unsigned int u; } v; v.f = f;
    unsigned int u = v.u;
    u += 0x7FFFu + ((u >> 16) & 1u);   // round-to-nearest-even
    return u >> 16;
}

// ws layout: float partial sums [0..31], int partial counts at dwords [32..63]
__global__ void ws_init_kernel(unsigned int* wsu){
    wsu[threadIdx.x] = 0u;     // 64 threads zero 64 dwords
}

__global__ void finalize_kernel(const float* wsf, float* out){
    float s = 0.f;
    int   c = 0;
    #pragma unroll
    for (int i = 0; i < 32; ++i){
        s += wsf[i];
        c += ((const int*)wsf)[32 + i];
    }
    out[0] = s / (float)c;
}

// launch_bounds(256,4): 128-reg unified cap (R3: 64 VGPR + 64 AGPR, no spill).
// (256,5) capped at 102 and SPILLED the accumulator (R2: FETCH +229MB, dur 401us).
__global__ __launch_bounds__(256, 4) void cossim_bce_main(
    const int*  __restrict__ zp,
    const float* __restrict__ x1,
    const float* __restrict__ x2,
    const float* __restrict__ tparm,
    const float* __restrict__ bparm,
    float* __restrict__ out,
    float* __restrict__ wsf)
{
    // 32 KB staging (two 128x64 bf16 tiles, XOR-swizzled), reused in the
    // epilogue as 4 x 8KB PER-WAVE transpose scratch (no cross-wave barriers).
    __shared__ __align__(16) unsigned short lds[2*128*64];
    __shared__ float nsh[256];   // [0..127]=1/||x1 row||, [128..255]=1/||x2 row||
    unsigned short* lA = lds;
    unsigned short* lB = lds + 128*64;

    const int t  = threadIdx.x;
    const int bx = blockIdx.x;   // M tile
    const int by = blockIdx.y;   // N tile
    const int bz = blockIdx.z;   // batch

    const float tv = *tparm;
    const float bv = *bparm;

    const float* x1base = x1 + ((size_t)(bz*NDIM) + by*128) * CDIM;
    const float* x2base = x2 + ((size_t)(bz*MDIM) + bx*128) * CDIM;

    const int lane = t & 63;
    const int w    = t >> 6;
    const int quad = lane >> 4;      // 0..3
    const int l16  = lane & 15;

    // wave w owns output rows w*32 .. w*32+31, ALL 128 cols:
    // acc[mi][n] = rows w*32+mi*16..+15, cols n*16..+15
    f32x4 acc[2][8];
    #pragma unroll
    for (int mi = 0; mi < 2; ++mi)
        #pragma unroll
        for (int n = 0; n < 8; ++n)
            acc[mi][n] = (f32x4){0.f, 0.f, 0.f, 0.f};

    float nsum = 0.f;                // per-thread norm partial (row t&127 of A or B)
    const int nrow = t & 127;

    // ---- two K-phases of 64 ----
    #pragma unroll
    for (int ph = 0; ph < 2; ++ph){
        // stage: f32 -> bf16, swizzled LDS writes (chunk ^ row&7)
        #pragma unroll
        for (int i = 0; i < 4; ++i){
            int chunk = i*256 + t;       // 1024 16B-chunks per tile
            int row = chunk >> 3;        // 0..127
            int pos = chunk & 7;         // 16B chunk within 64-col row
            int sw  = pos ^ (row & 7);
            {
                const float* p = x1base + row*CDIM + ph*64 + pos*8;
                float4 a = *(const float4*)p;
                float4 b = *(const float4*)(p + 4);
                uint4 pk;
                pk.x = f2bf(a.x) | (f2bf(a.y) << 16);
                pk.y = f2bf(a.z) | (f2bf(a.w) << 16);
                pk.z = f2bf(b.x) | (f2bf(b.y) << 16);
                pk.w = f2bf(b.z) | (f2bf(b.w) << 16);
                ((uint4*)lA)[row*8 + sw] = pk;
            }
            {
                const float* p = x2base + row*CDIM + ph*64 + pos*8;
                float4 a = *(const float4*)p;
                float4 b = *(const float4*)(p + 4);
                uint4 pk;
                pk.x = f2bf(a.x) | (f2bf(a.y) << 16);
                pk.y = f2bf(a.z) | (f2bf(a.w) << 16);
                pk.z = f2bf(b.x) | (f2bf(b.y) << 16);
                pk.w = f2bf(b.z) | (f2bf(b.w) << 16);
                ((uint4*)lB)[row*8 + sw] = pk;
            }
        }
        __syncthreads();

        // MFMA: 2 k-steps of 32 per phase
        #pragma unroll
        for (int kk = 0; kk < 2; ++kk){
            const int kc = kk*4 + quad;          // 16B k-chunk 0..7
            bf16x8 afr[2];
            #pragma unroll
            for (int mi = 0; mi < 2; ++mi){
                int row = w*32 + mi*16 + l16;
                afr[mi] = ((const bf16x8*)lA)[row*8 + (kc ^ (row & 7))];
            }
            #pragma unroll
            for (int g = 0; g < 2; ++g){         // B-frags in groups of 4 (reg pressure)
                bf16x8 bfr[4];
                #pragma unroll
                for (int nn = 0; nn < 4; ++nn){
                    int brow = (g*4 + nn)*16 + l16;
                    bfr[nn] = ((const bf16x8*)lB)[brow*8 + (kc ^ (brow & 7))];
                }
                #pragma unroll
                for (int mi = 0; mi < 2; ++mi)
                    #pragma unroll
                    for (int nn = 0; nn < 4; ++nn)
                        acc[mi][g*4+nn] = __builtin_amdgcn_mfma_f32_16x16x32_bf16(
                                            afr[mi], bfr[nn], acc[mi][g*4+nn], 0, 0, 0);
            }
        }

        // norm partials from the bf16 tiles (one row per thread)
        {
            const unsigned short* src = (t < 128) ? lA : lB;
            #pragma unroll
            for (int c = 0; c < 8; ++c){
                uint4 v = ((const uint4*)src)[nrow*8 + (c ^ (nrow & 7))];
                float f0 = bf2f(v.x & 0xffffu), f1 = bf2f(v.x >> 16);
                float f2 = bf2f(v.y & 0xffffu), f3 = bf2f(v.y >> 16);
                float f4 = bf2f(v.z & 0xffffu), f5 = bf2f(v.z >> 16);
                float f6 = bf2f(v.w & 0xffffu), f7 = bf2f(v.w >> 16);
                nsum += f0*f0 + f1*f1 + f2*f2 + f3*f3 + f4*f4 + f5*f5 + f6*f6 + f7*f7;
            }
        }
        __syncthreads();   // tile reads done before restage / scratch reuse
    }

    nsh[t] = 1.0f / sqrtf(fmaxf(nsum, 1e-16f));
    __syncthreads();       // nsh visible; staging tiles dead -> per-wave scratch

    // ---- barrier-free epilogue: each wave transposes its 32x128 block via
    //      its own 8KB scratch, then streams rows out (256B segments). ----
    float* scr = (float*)lds + w*2048;       // [32 rows][64 cols], col-rotated
    float* cosOut  = out + 1;
    float* maskOut = out + 1 + (size_t)BATCH*NDIM*MDIM;
    const size_t rowBase = (size_t)bz*NDIM*MDIM + (size_t)(by*128 + w*32)*MDIM + (size_t)(bx*128);

    float lnum = 0.f;
    int   lcnt = 0;

    #pragma unroll
    for (int h = 0; h < 2; ++h){             // col halves 0..63 / 64..127
        // scatter acc -> scratch (rotate col by 4*row: banks 2-way = free)
        #pragma unroll
        for (int mi = 0; mi < 2; ++mi){
            #pragma unroll
            for (int nn = 0; nn < 4; ++nn){
                int n = h*4 + nn;
                int col = n*16 + l16;                 // global col 0..127
                float in2 = nsh[128 + col];
                #pragma unroll
                for (int r = 0; r < 4; ++r){
                    int rowRel = mi*16 + quad*4 + r;  // 0..31
                    float in1 = nsh[w*32 + rowRel];
                    int sc = ((col & 63) + 4*rowRel) & 63;
                    scr[rowRel*64 + sc] = acc[mi][n][r] * in1 * in2;
                }
            }
        }
        // gather rows -> global (wave-local LDS dep: compiler emits lgkmcnt)
        #pragma unroll
        for (int i = 0; i < 8; ++i){
            int f = i*64 + lane;                      // 0..511
            int rowRel = f >> 4;                      // 0..31
            int c4 = f & 15;                          // float4 within 64-col half
            int sc4 = (c4*4 + 4*rowRel) & 63;
            f32x4 cs4 = *(const f32x4*)(scr + rowRel*64 + sc4);
            size_t idx = rowBase + (size_t)rowRel*MDIM + h*64 + c4*4;
            int4 z4 = *(const int4*)(zp + idx);

            f32x4 mk;
            float nl = 0.f;
            int   nc = 0;
            #pragma unroll
            for (int j = 0; j < 4; ++j){
                int zv = (&z4.x)[j];
                float cs = cs4[j];
                mk[j] = zv ? 1.0f : 0.0f;
                float y  = (float)zv * (tv*cs - bv);
                float nll = fmaxf(-y, 0.f) + __logf(1.0f + __expf(-fabsf(y)));
                nl += zv ? nll : 0.f;
                nc += zv ? 1 : 0;
            }
            lnum += nl;
            lcnt += nc;
            *(f32x4u*)(cosOut  + idx) = cs4;
            *(f32x4u*)(maskOut + idx) = mk;
        }
    }

    // ---- block-level loss reduction: 1 atomic pair per block ----
    #pragma unroll
    for (int off = 32; off > 0; off >>= 1){
        lnum += __shfl_down(lnum, off);
        lcnt += __shfl_down(lcnt, off);
    }
    __syncthreads();                 // waves done reading nsh; reuse for reduce
    if (lane == 0){ nsh[w] = lnum; ((int*)nsh)[4 + w] = lcnt; }
    __syncthreads();
    if (t == 0){
        float s = nsh[0] + nsh[1] + nsh[2] + nsh[3];
        int   c = ((int*)nsh)[4] + ((int*)nsh)[5] + ((int*)nsh)[6] + ((int*)nsh)[7];
        int cell = (bx + by*16 + bz*256) & 31;
        atomicAdd(wsf + cell, s);
        atomicAdd((int*)wsf + 32 + cell, c);
    }
}

extern "C" void kernel_launch(void* const* d_in, const int* in_sizes, int n_in,
                              void* d_out, int out_size, void* d_ws, size_t ws_size,
                              hipStream_t stream) {
    const int*   zp = (const int*)  d_in[0];
    const float* x1 = (const float*)d_in[1];
    const float* x2 = (const float*)d_in[2];
    const float* tp = (const float*)d_in[3];
    const float* bp = (const float*)d_in[4];
    float* out = (float*)d_out;
    float* wsf = (float*)d_ws;

    ws_init_kernel<<<1, 64, 0, stream>>>((unsigned int*)d_ws);
    dim3 grid(MDIM/128, NDIM/128, BATCH);
    cossim_bce_main<<<grid, 256, 0, stream>>>(zp, x1, x2, tp, bp, out, wsf);
    finalize_kernel<<<1, 1, 0, stream>>>(wsf, out);
}

// Round 6
// 131.490 us; speedup vs baseline: 2.3708x; 1.2905x over previous
//
#include <hip/hip_runtime.h>
#include <hip/hip_bf16.h>

#define BATCH 8
#define NDIM  2048
#define MDIM  2048
#define CDIM  128

typedef __attribute__((ext_vector_type(8))) short bf16x8;
typedef __attribute__((ext_vector_type(4))) float f32x4;
// 4B-aligned float4 for the (out+1)-offset misaligned global stores
typedef __attribute__((ext_vector_type(4), aligned(4))) float f32x4u;

__device__ __forceinline__ float bf2f(unsigned int u16){
    union { unsigned int u; float f; } v; v.u = u16 << 16; return v.f;
}
__device__ __forceinline__ unsigned int f2bf(float f){
    union { float f; unsigned int u; } v; v.f = f;
    unsigned int u = v.u;
    u += 0x7FFFu + ((u >> 16) & 1u);   // round-to-nearest-even
    return u >> 16;
}

// ws layout: float partial sums [0..31], int partial counts at dwords [32..63]
__global__ void ws_init_kernel(unsigned int* wsu){
    wsu[threadIdx.x] = 0u;     // 64 threads zero 64 dwords
}

__global__ void finalize_kernel(const float* wsf, float* out){
    float s = 0.f;
    int   c = 0;
    #pragma unroll
    for (int i = 0; i < 32; ++i){
        s += wsf[i];
        c += ((const int*)wsf)[32 + i];
    }
    out[0] = s / (float)c;
}

// Tile: 64 (N, x1 rows) x 128 (M, x2 rows; output-contiguous dim -> 512B row
// segments, the store pattern that measured best: R5 WRITE 369MB vs R4 640MB).
// 4 waves; wave owns 16 rows x 128 cols (acc = 32 AGPR).
// launch_bounds(256,5): 102-reg unified cap; est. peak ~85. R2 lesson: if
// VGPR_Count collapses + FETCH explodes, the cap spilled -> back off to (256,4).
__global__ __launch_bounds__(256, 5) void cossim_bce_main(
    const int*  __restrict__ zp,
    const float* __restrict__ x1,
    const float* __restrict__ x2,
    const float* __restrict__ tparm,
    const float* __restrict__ bparm,
    float* __restrict__ out,
    float* __restrict__ wsf)
{
    // 24KB staging (lA[64][64] + lB[128][64] bf16, XOR-swizzled), reused in the
    // epilogue as 4 x 4KB per-wave transpose scratch (no cross-wave barriers).
    __shared__ __align__(16) unsigned short lds[(64 + 128) * 64];
    __shared__ float nsh[192];   // [0..63]=1/||x1 row||, [64..191]=1/||x2 row||
    unsigned short* lA = lds;            // [64][64]
    unsigned short* lB = lds + 64*64;    // [128][64]

    const int t  = threadIdx.x;
    const int bx = blockIdx.x;   // M tile (16)
    const int by = blockIdx.y;   // N tile (32)
    const int bz = blockIdx.z;   // batch

    const float tv = *tparm;
    const float bv = *bparm;

    const float* x1base = x1 + ((size_t)(bz*NDIM) + by*64 ) * CDIM;
    const float* x2base = x2 + ((size_t)(bz*MDIM) + bx*128) * CDIM;

    const int lane = t & 63;
    const int w    = t >> 6;
    const int quad = lane >> 4;      // 0..3
    const int l16  = lane & 15;
    const int hi   = lane >> 5;      // 0..1
    const int c4   = lane & 31;

    // wave w: output rows w*16 .. w*16+15 (row-in-wave = quad*4+r), cols n*16+l16
    f32x4 acc[8];
    #pragma unroll
    for (int n = 0; n < 8; ++n)
        acc[n] = (f32x4){0.f, 0.f, 0.f, 0.f};

    float nsum = 0.f;                // norm partial: t<64 -> x1 row t; 64..191 -> x2 row t-64

    // ---- two K-phases of 64 ----
    #pragma unroll
    for (int ph = 0; ph < 2; ++ph){
        // stage: f32 -> bf16, swizzled LDS writes (chunk ^ row&7)
        #pragma unroll
        for (int i = 0; i < 6; ++i){
            int chunk = i*256 + t;           // 0..1535 16B-chunks
            const float* srcb;
            uint4* dst;
            int row, pos;
            if (i < 2){                      // lA: chunks 0..511
                row = chunk >> 3; pos = chunk & 7;
                srcb = x1base; dst = (uint4*)lA;
            } else {                         // lB: chunks 512..1535
                int c2 = chunk - 512;
                row = c2 >> 3; pos = c2 & 7;
                srcb = x2base; dst = (uint4*)lB;
            }
            const float* p = srcb + row*CDIM + ph*64 + pos*8;
            float4 a = *(const float4*)p;
            float4 b = *(const float4*)(p + 4);
            uint4 pk;
            pk.x = f2bf(a.x) | (f2bf(a.y) << 16);
            pk.y = f2bf(a.z) | (f2bf(a.w) << 16);
            pk.z = f2bf(b.x) | (f2bf(b.y) << 16);
            pk.w = f2bf(b.z) | (f2bf(b.w) << 16);
            dst[row*8 + (pos ^ (row & 7))] = pk;
        }
        __syncthreads();

        // MFMA: 2 k-steps of 32 per phase
        #pragma unroll
        for (int kk = 0; kk < 2; ++kk){
            const int kc = kk*4 + quad;              // 16B k-chunk 0..7
            const int arow = w*16 + l16;
            bf16x8 afr = ((const bf16x8*)lA)[arow*8 + (kc ^ (arow & 7))];
            #pragma unroll
            for (int g = 0; g < 2; ++g){             // B-frags in groups of 4
                bf16x8 bfr[4];
                #pragma unroll
                for (int nn = 0; nn < 4; ++nn){
                    int brow = (g*4 + nn)*16 + l16;
                    bfr[nn] = ((const bf16x8*)lB)[brow*8 + (kc ^ (brow & 7))];
                }
                #pragma unroll
                for (int nn = 0; nn < 4; ++nn)
                    acc[g*4+nn] = __builtin_amdgcn_mfma_f32_16x16x32_bf16(
                                    afr, bfr[nn], acc[g*4+nn], 0, 0, 0);
            }
        }

        // norm partials from the bf16 tiles (one row per thread, 192 active)
        if (t < 192){
            const uint4* base; int row;
            if (t < 64){ base = (const uint4*)lA; row = t; }
            else       { base = (const uint4*)lB; row = t - 64; }
            #pragma unroll
            for (int c = 0; c < 8; ++c){
                uint4 v = base[row*8 + (c ^ (row & 7))];
                float f0 = bf2f(v.x & 0xffffu), f1 = bf2f(v.x >> 16);
                float f2 = bf2f(v.y & 0xffffu), f3 = bf2f(v.y >> 16);
                float f4 = bf2f(v.z & 0xffffu), f5 = bf2f(v.z >> 16);
                float f6 = bf2f(v.w & 0xffffu), f7 = bf2f(v.w >> 16);
                nsum += f0*f0 + f1*f1 + f2*f2 + f3*f3 + f4*f4 + f5*f5 + f6*f6 + f7*f7;
            }
        }
        __syncthreads();   // tile reads done before restage / scratch reuse
    }

    if (t < 192) nsh[t] = 1.0f / sqrtf(fmaxf(nsum, 1e-16f));
    __syncthreads();       // nsh visible; staging tiles dead -> per-wave scratch

    // preload norms to registers (nsh then idle until final reduce)
    float in1[4], in2[8];
    #pragma unroll
    for (int r = 0; r < 4; ++r) in1[r] = nsh[w*16 + quad*4 + r];
    #pragma unroll
    for (int n = 0; n < 8; ++n) in2[n] = nsh[64 + n*16 + l16];

    // ---- barrier-free epilogue: per-wave 8x128 transpose scratch, 2 rounds ----
    float* scr = (float*)lds + w*1024;       // [8][128] f32, col-rotated by sr*4
    float* cosOut  = out + 1;
    float* maskOut = out + 1 + (size_t)BATCH*NDIM*MDIM;
    const size_t rowBase = (size_t)bz*NDIM*MDIM + (size_t)(by*64 + w*16)*MDIM + (size_t)(bx*128);

    float lnum = 0.f;
    int   lcnt = 0;

    // prefetch z for round 0 (rows i*4 + hi)
    int4 zpre[4];
    #pragma unroll
    for (int i = 0; i < 4; ++i)
        zpre[i] = *(const int4*)(zp + rowBase + (size_t)(i*4 + hi)*MDIM + c4*4);

    #pragma unroll
    for (int rr = 0; rr < 2; ++rr){
        // scatter: rows quad*4 + rr*2 + j -> scr row sr = quad*2+j
        #pragma unroll
        for (int n = 0; n < 8; ++n){
            #pragma unroll
            for (int j = 0; j < 2; ++j){
                int r  = rr*2 + j;
                int sr = quad*2 + j;
                scr[sr*128 + ((n*16 + l16 + sr*4) & 127)] = acc[n][r] * in1[r] * in2[n];
            }
        }
        // gather + math + streaming stores (wave-local LDS dep -> lgkmcnt only)
        #pragma unroll
        for (int i = 0; i < 4; ++i){
            int sr  = i*2 + hi;
            int col = (c4*4 + sr*4) & 127;
            f32x4 cs4 = *(const f32x4*)(scr + sr*128 + col);
            int rowRel = i*4 + rr*2 + hi;
            size_t idx = rowBase + (size_t)rowRel*MDIM + c4*4;

            int4 z4 = zpre[i];
            if (rr == 0)   // issue round-1 z load now (rows +2)
                zpre[i] = *(const int4*)(zp + idx + (size_t)2*MDIM);

            f32x4 mk;
            float nl = 0.f;
            int   nc = 0;
            #pragma unroll
            for (int j = 0; j < 4; ++j){
                int zv = (&z4.x)[j];
                float cs = cs4[j];
                mk[j] = zv ? 1.0f : 0.0f;
                float y  = (float)zv * (tv*cs - bv);
                float nll = fmaxf(-y, 0.f) + __logf(1.0f + __expf(-fabsf(y)));
                nl += zv ? nll : 0.f;
                nc += zv ? 1 : 0;
            }
            lnum += nl;
            lcnt += nc;
            *(f32x4u*)(cosOut  + idx) = cs4;
            *(f32x4u*)(maskOut + idx) = mk;
        }
    }

    // ---- block-level loss reduction: 1 atomic pair per block ----
    #pragma unroll
    for (int off = 32; off > 0; off >>= 1){
        lnum += __shfl_down(lnum, off);
        lcnt += __shfl_down(lcnt, off);
    }
    __syncthreads();                 // all waves done with nsh; reuse for reduce
    if (lane == 0){ nsh[w] = lnum; ((int*)nsh)[4 + w] = lcnt; }
    __syncthreads();
    if (t == 0){
        float s = nsh[0] + nsh[1] + nsh[2] + nsh[3];
        int   c = ((int*)nsh)[4] + ((int*)nsh)[5] + ((int*)nsh)[6] + ((int*)nsh)[7];
        int cell = (bx + by*16 + bz*512) & 31;
        atomicAdd(wsf + cell, s);
        atomicAdd((int*)wsf + 32 + cell, c);
    }
}

extern "C" void kernel_launch(void* const* d_in, const int* in_sizes, int n_in,
                              void* d_out, int out_size, void* d_ws, size_t ws_size,
                              hipStream_t stream) {
    const int*   zp = (const int*)  d_in[0];
    const float* x1 = (const float*)d_in[1];
    const float* x2 = (const float*)d_in[2];
    const float* tp = (const float*)d_in[3];
    const float* bp = (const float*)d_in[4];
    float* out = (float*)d_out;
    float* wsf = (float*)d_ws;

    ws_init_kernel<<<1, 64, 0, stream>>>((unsigned int*)d_ws);
    dim3 grid(MDIM/128, NDIM/64, BATCH);
    cossim_bce_main<<<grid, 256, 0, stream>>>(zp, x1, x2, tp, bp, out, wsf);
    finalize_kernel<<<1, 1, 0, stream>>>(wsf, out);
}

// Round 7
// 123.191 us; speedup vs baseline: 2.5305x; 1.0674x over previous
//
#include <hip/hip_runtime.h>
#include <hip/hip_bf16.h>

#define BATCH 8
#define NDIM  2048
#define MDIM  2048
#define CDIM  128

typedef __attribute__((ext_vector_type(8))) short bf16x8;
typedef __attribute__((ext_vector_type(4))) float f32x4;
// 4B-aligned float4 for the (out+1)-offset misaligned global stores
typedef __attribute__((ext_vector_type(4), aligned(4))) float f32x4u;

__device__ __forceinline__ float bf2f(unsigned int u16){
    union { unsigned int u; float f; } v; v.u = u16 << 16; return v.f;
}
__device__ __forceinline__ unsigned int f2bf(float f){
    union { float f; unsigned int u; } v; v.f = f;
    unsigned int u = v.u;
    u += 0x7FFFu + ((u >> 16) & 1u);   // round-to-nearest-even
    return u >> 16;
}

__device__ __forceinline__ void gload_lds16(const void* g, void* l){
    __builtin_amdgcn_global_load_lds(
        (const __attribute__((address_space(1))) void*)g,
        (__attribute__((address_space(3))) void*)l, 16, 0, 0);
}

// cells: float partial sums [0..31], int partial counts at dwords [32..63]
__global__ void ws_init_kernel(unsigned int* cells){
    cells[threadIdx.x] = 0u;     // 64 threads zero 64 dwords
}

__global__ void finalize_kernel(const float* cells, float* out){
    float s = 0.f;
    int   c = 0;
    #pragma unroll
    for (int i = 0; i < 32; ++i){
        s += cells[i];
        c += ((const int*)cells)[32 + i];
    }
    out[0] = s / (float)c;
}

// ---------------- pre-pass: f32 -> bf16 + per-row 1/||row|| ----------------
// 32768 rows (16384 x1 then 16384 x2) x 128 cols. 16 lanes per row.
__global__ __launch_bounds__(256) void prep_kernel(
    const float* __restrict__ x1, const float* __restrict__ x2,
    unsigned short* __restrict__ xb, float* __restrict__ inv)
{
    int gt  = blockIdx.x*256 + threadIdx.x;   // 0..524287
    int row = gt >> 4;                        // 0..32767
    int seg = gt & 15;                        // 8-elem segment
    const float* src = (row < 16384) ? (x1 + (size_t)row*128)
                                     : (x2 + (size_t)(row - 16384)*128);
    float4 a = *(const float4*)(src + seg*8);
    float4 b = *(const float4*)(src + seg*8 + 4);
    uint4 pk;
    pk.x = f2bf(a.x) | (f2bf(a.y) << 16);
    pk.y = f2bf(a.z) | (f2bf(a.w) << 16);
    pk.z = f2bf(b.x) | (f2bf(b.y) << 16);
    pk.w = f2bf(b.z) | (f2bf(b.w) << 16);
    ((uint4*)xb)[(size_t)row*16 + seg] = pk;

    // norm of the ROUNDED values (matches prior rounds' numerics)
    float f0 = bf2f(pk.x & 0xffffu), f1 = bf2f(pk.x >> 16);
    float f2 = bf2f(pk.y & 0xffffu), f3 = bf2f(pk.y >> 16);
    float f4 = bf2f(pk.z & 0xffffu), f5 = bf2f(pk.z >> 16);
    float f6 = bf2f(pk.w & 0xffffu), f7 = bf2f(pk.w >> 16);
    float s = f0*f0 + f1*f1 + f2*f2 + f3*f3 + f4*f4 + f5*f5 + f6*f6 + f7*f7;
    s += __shfl_xor(s, 1);
    s += __shfl_xor(s, 2);
    s += __shfl_xor(s, 4);
    s += __shfl_xor(s, 8);
    if (seg == 0) inv[row] = 1.0f / sqrtf(fmaxf(s, 1e-16f));
}

// ---------------- main (fast path): B via global_load_lds, A direct ----------------
// Tile 64 (N) x 128 (M); 4 waves; wave owns 16 rows x 128 cols (acc = 32 AGPR).
__global__ __launch_bounds__(256, 5) void cossim_bce_fast(
    const int*  __restrict__ zp,
    const unsigned short* __restrict__ xb,
    const float* __restrict__ inv,
    const float* __restrict__ tparm,
    const float* __restrict__ bparm,
    float* __restrict__ out,
    float* __restrict__ cells)
{
    // 16 KB: B-phase tile [128][64] bf16 (linear chunks, swizzle folded into
    // the global SOURCE address); reused as 4 x 4KB per-wave transpose scratch.
    __shared__ __align__(16) unsigned short lB[128*64];

    const int t  = threadIdx.x;
    const int bx = blockIdx.x;   // M tile (16)
    const int by = blockIdx.y;   // N tile (32)
    const int bz = blockIdx.z;   // batch

    const float tv = *tparm;
    const float bv = *bparm;

    const unsigned short* x1b = xb;                          // 16384 x 128
    const unsigned short* x2b = xb + (size_t)16384*128;      // 16384 x 128
    const int x1r0 = bz*NDIM + by*64;
    const int x2r0 = bz*MDIM + bx*128;

    const int lane = t & 63;
    const int w    = t >> 6;
    const int quad = lane >> 4;      // 0..3
    const int l16  = lane & 15;
    const int hi   = lane >> 5;      // 0..1
    const int c4   = lane & 31;

    f32x4 acc[8];
    #pragma unroll
    for (int n = 0; n < 8; ++n)
        acc[n] = (f32x4){0.f, 0.f, 0.f, 0.f};

    const size_t rowBase = (size_t)bz*NDIM*MDIM + (size_t)(by*64 + w*16)*MDIM + (size_t)(bx*128);

    // stage helper data: chunk = i*256 + t; row = chunk>>3; swizzled src pos
    // so that LDS slot row*8+p' holds B[row][p'^(row&7)] -> consumer reads
    // slot row*8 + (kc ^ (row&7)) to get B[row][kc] (bank-conflict-free).
    // ---- phase 0 stage ----
    #pragma unroll
    for (int i = 0; i < 4; ++i){
        int chunk = i*256 + t;
        int row = chunk >> 3, pp = chunk & 7;
        int srcpos = pp ^ (row & 7);
        gload_lds16(x2b + ((size_t)(x2r0 + row))*128 + 0*64 + srcpos*8,
                    lB + (size_t)(i*256 + w*64)*8);
    }
    __syncthreads();

    // norms (L3-hot scalar loads; issued early, consumed in epilogue)
    float in1[4], in2[8];
    #pragma unroll
    for (int r = 0; r < 4; ++r) in1[r] = inv[x1r0 + w*16 + quad*4 + r];
    #pragma unroll
    for (int n = 0; n < 8; ++n) in2[n] = inv[16384 + x2r0 + n*16 + l16];

    const unsigned short* aRow = x1b + ((size_t)(x1r0 + w*16 + l16))*128 + quad*8;

    // ---- phase 0 MFMA (k-steps s=0,1) ----
    #pragma unroll
    for (int kk = 0; kk < 2; ++kk){
        bf16x8 afr = *(const bf16x8*)(aRow + kk*32);
        const int kc = kk*4 + quad;
        #pragma unroll
        for (int g = 0; g < 2; ++g){
            bf16x8 bfr[4];
            #pragma unroll
            for (int nn = 0; nn < 4; ++nn){
                int brow = (g*4 + nn)*16 + l16;
                bfr[nn] = ((const bf16x8*)lB)[brow*8 + (kc ^ (brow & 7))];
            }
            #pragma unroll
            for (int nn = 0; nn < 4; ++nn)
                acc[g*4+nn] = __builtin_amdgcn_mfma_f32_16x16x32_bf16(
                                afr, bfr[nn], acc[g*4+nn], 0, 0, 0);
        }
    }
    __syncthreads();   // phase-0 reads done

    // ---- phase 1 stage + round-0 z prefetch (lands during MFMA phase 1) ----
    #pragma unroll
    for (int i = 0; i < 4; ++i){
        int chunk = i*256 + t;
        int row = chunk >> 3, pp = chunk & 7;
        int srcpos = pp ^ (row & 7);
        gload_lds16(x2b + ((size_t)(x2r0 + row))*128 + 1*64 + srcpos*8,
                    lB + (size_t)(i*256 + w*64)*8);
    }
    int4 zpre[4];
    #pragma unroll
    for (int i = 0; i < 4; ++i)
        zpre[i] = *(const int4*)(zp + rowBase + (size_t)(i*4 + hi)*MDIM + c4*4);
    __syncthreads();

    // ---- phase 1 MFMA (k-steps s=2,3) ----
    #pragma unroll
    for (int kk = 0; kk < 2; ++kk){
        bf16x8 afr = *(const bf16x8*)(aRow + 64 + kk*32);
        const int kc = kk*4 + quad;
        #pragma unroll
        for (int g = 0; g < 2; ++g){
            bf16x8 bfr[4];
            #pragma unroll
            for (int nn = 0; nn < 4; ++nn){
                int brow = (g*4 + nn)*16 + l16;
                bfr[nn] = ((const bf16x8*)lB)[brow*8 + (kc ^ (brow & 7))];
            }
            #pragma unroll
            for (int nn = 0; nn < 4; ++nn)
                acc[g*4+nn] = __builtin_amdgcn_mfma_f32_16x16x32_bf16(
                                afr, bfr[nn], acc[g*4+nn], 0, 0, 0);
        }
    }
    __syncthreads();   // B dead -> per-wave scratch reuse

    // ---- barrier-free epilogue: per-wave 8x128 transpose scratch, 2 rounds ----
    float* scr = (float*)lB + w*1024;        // [8][128] f32, col-rotated by sr*4
    float* cosOut  = out + 1;
    float* maskOut = out + 1 + (size_t)BATCH*NDIM*MDIM;

    float lnum = 0.f;
    int   lcnt = 0;

    #pragma unroll
    for (int rr = 0; rr < 2; ++rr){
        // scatter: rows quad*4 + rr*2 + j -> scr row sr = quad*2+j
        #pragma unroll
        for (int n = 0; n < 8; ++n){
            #pragma unroll
            for (int j = 0; j < 2; ++j){
                int r  = rr*2 + j;
                int sr = quad*2 + j;
                scr[sr*128 + ((n*16 + l16 + sr*4) & 127)] = acc[n][r] * in1[r] * in2[n];
            }
        }
        // gather + math + streaming stores (wave-local LDS dep -> lgkmcnt only)
        #pragma unroll
        for (int i = 0; i < 4; ++i){
            int sr  = i*2 + hi;
            int col = (c4*4 + sr*4) & 127;
            f32x4 cs4 = *(const f32x4*)(scr + sr*128 + col);
            int rowRel = i*4 + rr*2 + hi;
            size_t idx = rowBase + (size_t)rowRel*MDIM + c4*4;

            int4 z4 = zpre[i];
            if (rr == 0)   // issue round-1 z load now (rows +2)
                zpre[i] = *(const int4*)(zp + idx + (size_t)2*MDIM);

            f32x4 mk;
            float nl = 0.f;
            int   nc = 0;
            #pragma unroll
            for (int j = 0; j < 4; ++j){
                int zv = (&z4.x)[j];
                float cs = cs4[j];
                mk[j] = zv ? 1.0f : 0.0f;
                float y  = (float)zv * (tv*cs - bv);
                float nll = fmaxf(-y, 0.f) + __logf(1.0f + __expf(-fabsf(y)));
                nl += zv ? nll : 0.f;
                nc += zv ? 1 : 0;
            }
            lnum += nl;
            lcnt += nc;
            *(f32x4u*)(cosOut  + idx) = cs4;
            *(f32x4u*)(maskOut + idx) = mk;
        }
    }

    // ---- block-level loss reduction: 1 atomic pair per block ----
    #pragma unroll
    for (int off = 32; off > 0; off >>= 1){
        lnum += __shfl_down(lnum, off);
        lcnt += __shfl_down(lcnt, off);
    }
    __syncthreads();                 // scratch reads done; reuse for reduce
    float* redf = (float*)lB;
    int*   redi = (int*)lB + 8;
    if (lane == 0){ redf[w] = lnum; redi[w] = lcnt; }
    __syncthreads();
    if (t == 0){
        float s = redf[0] + redf[1] + redf[2] + redf[3];
        int   c = redi[0] + redi[1] + redi[2] + redi[3];
        int cell = (bx + by*16 + bz*512) & 31;
        atomicAdd(cells + cell, s);
        atomicAdd((int*)cells + 32 + cell, c);
    }
}

// ---------------- fallback (proven R6 kernel, used if ws too small) ----------------
__global__ __launch_bounds__(256, 5) void cossim_bce_main(
    const int*  __restrict__ zp,
    const float* __restrict__ x1,
    const float* __restrict__ x2,
    const float* __restrict__ tparm,
    const float* __restrict__ bparm,
    float* __restrict__ out,
    float* __restrict__ wsf)
{
    __shared__ __align__(16) unsigned short lds[(64 + 128) * 64];
    __shared__ float nsh[192];
    unsigned short* lA = lds;
    unsigned short* lB = lds + 64*64;

    const int t  = threadIdx.x;
    const int bx = blockIdx.x;
    const int by = blockIdx.y;
    const int bz = blockIdx.z;

    const float tv = *tparm;
    const float bv = *bparm;

    const float* x1base = x1 + ((size_t)(bz*NDIM) + by*64 ) * CDIM;
    const float* x2base = x2 + ((size_t)(bz*MDIM) + bx*128) * CDIM;

    const int lane = t & 63;
    const int w    = t >> 6;
    const int quad = lane >> 4;
    const int l16  = lane & 15;
    const int hi   = lane >> 5;
    const int c4   = lane & 31;

    f32x4 acc[8];
    #pragma unroll
    for (int n = 0; n < 8; ++n)
        acc[n] = (f32x4){0.f, 0.f, 0.f, 0.f};

    float nsum = 0.f;

    #pragma unroll
    for (int ph = 0; ph < 2; ++ph){
        #pragma unroll
        for (int i = 0; i < 6; ++i){
            int chunk = i*256 + t;
            const float* srcb;
            uint4* dst;
            int row, pos;
            if (i < 2){
                row = chunk >> 3; pos = chunk & 7;
                srcb = x1base; dst = (uint4*)lA;
            } else {
                int c2 = chunk - 512;
                row = c2 >> 3; pos = c2 & 7;
                srcb = x2base; dst = (uint4*)lB;
            }
            const float* p = srcb + row*CDIM + ph*64 + pos*8;
            float4 a = *(const float4*)p;
            float4 b = *(const float4*)(p + 4);
            uint4 pk;
            pk.x = f2bf(a.x) | (f2bf(a.y) << 16);
            pk.y = f2bf(a.z) | (f2bf(a.w) << 16);
            pk.z = f2bf(b.x) | (f2bf(b.y) << 16);
            pk.w = f2bf(b.z) | (f2bf(b.w) << 16);
            dst[row*8 + (pos ^ (row & 7))] = pk;
        }
        __syncthreads();

        #pragma unroll
        for (int kk = 0; kk < 2; ++kk){
            const int kc = kk*4 + quad;
            const int arow = w*16 + l16;
            bf16x8 afr = ((const bf16x8*)lA)[arow*8 + (kc ^ (arow & 7))];
            #pragma unroll
            for (int g = 0; g < 2; ++g){
                bf16x8 bfr[4];
                #pragma unroll
                for (int nn = 0; nn < 4; ++nn){
                    int brow = (g*4 + nn)*16 + l16;
                    bfr[nn] = ((const bf16x8*)lB)[brow*8 + (kc ^ (brow & 7))];
                }
                #pragma unroll
                for (int nn = 0; nn < 4; ++nn)
                    acc[g*4+nn] = __builtin_amdgcn_mfma_f32_16x16x32_bf16(
                                    afr, bfr[nn], acc[g*4+nn], 0, 0, 0);
            }
        }

        if (t < 192){
            const uint4* base; int row;
            if (t < 64){ base = (const uint4*)lA; row = t; }
            else       { base = (const uint4*)lB; row = t - 64; }
            #pragma unroll
            for (int c = 0; c < 8; ++c){
                uint4 v = base[row*8 + (c ^ (row & 7))];
                float f0 = bf2f(v.x & 0xffffu), f1 = bf2f(v.x >> 16);
                float f2 = bf2f(v.y & 0xffffu), f3 = bf2f(v.y >> 16);
                float f4 = bf2f(v.z & 0xffffu), f5 = bf2f(v.z >> 16);
                float f6 = bf2f(v.w & 0xffffu), f7 = bf2f(v.w >> 16);
                nsum += f0*f0 + f1*f1 + f2*f2 + f3*f3 + f4*f4 + f5*f5 + f6*f6 + f7*f7;
            }
        }
        __syncthreads();
    }

    if (t < 192) nsh[t] = 1.0f / sqrtf(fmaxf(nsum, 1e-16f));
    __syncthreads();

    float in1[4], in2[8];
    #pragma unroll
    for (int r = 0; r < 4; ++r) in1[r] = nsh[w*16 + quad*4 + r];
    #pragma unroll
    for (int n = 0; n < 8; ++n) in2[n] = nsh[64 + n*16 + l16];

    float* scr = (float*)lds + w*1024;
    float* cosOut  = out + 1;
    float* maskOut = out + 1 + (size_t)BATCH*NDIM*MDIM;
    const size_t rowBase = (size_t)bz*NDIM*MDIM + (size_t)(by*64 + w*16)*MDIM + (size_t)(bx*128);

    float lnum = 0.f;
    int   lcnt = 0;

    int4 zpre[4];
    #pragma unroll
    for (int i = 0; i < 4; ++i)
        zpre[i] = *(const int4*)(zp + rowBase + (size_t)(i*4 + hi)*MDIM + c4*4);

    #pragma unroll
    for (int rr = 0; rr < 2; ++rr){
        #pragma unroll
        for (int n = 0; n < 8; ++n){
            #pragma unroll
            for (int j = 0; j < 2; ++j){
                int r  = rr*2 + j;
                int sr = quad*2 + j;
                scr[sr*128 + ((n*16 + l16 + sr*4) & 127)] = acc[n][r] * in1[r] * in2[n];
            }
        }
        #pragma unroll
        for (int i = 0; i < 4; ++i){
            int sr  = i*2 + hi;
            int col = (c4*4 + sr*4) & 127;
            f32x4 cs4 = *(const f32x4*)(scr + sr*128 + col);
            int rowRel = i*4 + rr*2 + hi;
            size_t idx = rowBase + (size_t)rowRel*MDIM + c4*4;

            int4 z4 = zpre[i];
            if (rr == 0)
                zpre[i] = *(const int4*)(zp + idx + (size_t)2*MDIM);

            f32x4 mk;
            float nl = 0.f;
            int   nc = 0;
            #pragma unroll
            for (int j = 0; j < 4; ++j){
                int zv = (&z4.x)[j];
                float cs = cs4[j];
                mk[j] = zv ? 1.0f : 0.0f;
                float y  = (float)zv * (tv*cs - bv);
                float nll = fmaxf(-y, 0.f) + __logf(1.0f + __expf(-fabsf(y)));
                nl += zv ? nll : 0.f;
                nc += zv ? 1 : 0;
            }
            lnum += nl;
            lcnt += nc;
            *(f32x4u*)(cosOut  + idx) = cs4;
            *(f32x4u*)(maskOut + idx) = mk;
        }
    }

    #pragma unroll
    for (int off = 32; off > 0; off >>= 1){
        lnum += __shfl_down(lnum, off);
        lcnt += __shfl_down(lcnt, off);
    }
    __syncthreads();
    if (lane == 0){ nsh[w] = lnum; ((int*)nsh)[4 + w] = lcnt; }
    __syncthreads();
    if (t == 0){
        float s = nsh[0] + nsh[1] + nsh[2] + nsh[3];
        int   c = ((int*)nsh)[4] + ((int*)nsh)[5] + ((int*)nsh)[6] + ((int*)nsh)[7];
        int cell = (bx + by*16 + bz*512) & 31;
        atomicAdd(wsf + cell, s);
        atomicAdd((int*)wsf + 32 + cell, c);
    }
}

extern "C" void kernel_launch(void* const* d_in, const int* in_sizes, int n_in,
                              void* d_out, int out_size, void* d_ws, size_t ws_size,
                              hipStream_t stream) {
    const int*   zp = (const int*)  d_in[0];
    const float* x1 = (const float*)d_in[1];
    const float* x2 = (const float*)d_in[2];
    const float* tp = (const float*)d_in[3];
    const float* bp = (const float*)d_in[4];
    float* out = (float*)d_out;

    // ws fast-path layout: xb bf16[32768*128] (8 MB) | inv f32[32768] (128 KB) | cells (256 B)
    const size_t WS_NEEDED = (size_t)8*1024*1024 + 32768*4 + 256;
    dim3 grid(MDIM/128, NDIM/64, BATCH);

    if (ws_size >= WS_NEEDED){
        unsigned short* xb  = (unsigned short*)d_ws;
        float* inv   = (float*)((char*)d_ws + (size_t)8*1024*1024);
        float* cells = inv + 32768;
        ws_init_kernel<<<1, 64, 0, stream>>>((unsigned int*)cells);
        prep_kernel<<<2048, 256, 0, stream>>>(x1, x2, xb, inv);
        cossim_bce_fast<<<grid, 256, 0, stream>>>(zp, xb, inv, tp, bp, out, cells);
        finalize_kernel<<<1, 1, 0, stream>>>(cells, out);
    } else {
        float* wsf = (float*)d_ws;
        ws_init_kernel<<<1, 64, 0, stream>>>((unsigned int*)d_ws);
        cossim_bce_main<<<grid, 256, 0, stream>>>(zp, x1, x2, tp, bp, out, wsf);
        finalize_kernel<<<1, 1, 0, stream>>>(wsf, out);
    }
}

// Round 8
// 118.554 us; speedup vs baseline: 2.6295x; 1.0391x over previous
//
#include <hip/hip_runtime.h>
#include <hip/hip_bf16.h>

#define BATCH 8
#define NDIM  2048
#define MDIM  2048
#define CDIM  128

typedef __attribute__((ext_vector_type(8))) short bf16x8;
typedef __attribute__((ext_vector_type(4))) float f32x4;
// 4B-aligned float4 for the (out+1)-offset misaligned global stores
typedef __attribute__((ext_vector_type(4), aligned(4))) float f32x4u;

__device__ __forceinline__ float bf2f(unsigned int u16){
    union { unsigned int u; float f; } v; v.u = u16 << 16; return v.f;
}
__device__ __forceinline__ unsigned int f2bf(float f){
    union { float f; unsigned int u; } v; v.f = f;
    unsigned int u = v.u;
    u += 0x7FFFu + ((u >> 16) & 1u);   // round-to-nearest-even
    return u >> 16;
}

__device__ __forceinline__ void gload_lds16(const void* g, void* l){
    __builtin_amdgcn_global_load_lds(
        (const __attribute__((address_space(1))) void*)g,
        (__attribute__((address_space(3))) void*)l, 16, 0, 0);
}

__global__ void finalize_kernel(const float* cells, float* out){
    float s = 0.f;
    int   c = 0;
    #pragma unroll
    for (int i = 0; i < 32; ++i){
        s += cells[i];
        c += ((const int*)cells)[32 + i];
    }
    out[0] = s / (float)c;
}

// ---------------- pre-pass: f32 -> bf16 + per-row 1/||row|| + cells zero ----------------
// 32768 rows (16384 x1 then 16384 x2) x 128 cols. 16 lanes per row.
__global__ __launch_bounds__(256) void prep_kernel(
    const float* __restrict__ x1, const float* __restrict__ x2,
    unsigned short* __restrict__ xb, float* __restrict__ inv,
    unsigned int* __restrict__ cells)
{
    if (blockIdx.x == 0 && threadIdx.x < 64) cells[threadIdx.x] = 0u;

    int gt  = blockIdx.x*256 + threadIdx.x;   // 0..524287
    int row = gt >> 4;                        // 0..32767
    int seg = gt & 15;                        // 8-elem segment
    const float* src = (row < 16384) ? (x1 + (size_t)row*128)
                                     : (x2 + (size_t)(row - 16384)*128);
    float4 a = *(const float4*)(src + seg*8);
    float4 b = *(const float4*)(src + seg*8 + 4);
    uint4 pk;
    pk.x = f2bf(a.x) | (f2bf(a.y) << 16);
    pk.y = f2bf(a.z) | (f2bf(a.w) << 16);
    pk.z = f2bf(b.x) | (f2bf(b.y) << 16);
    pk.w = f2bf(b.z) | (f2bf(b.w) << 16);
    ((uint4*)xb)[(size_t)row*16 + seg] = pk;

    // norm of the ROUNDED values (matches prior rounds' numerics)
    float f0 = bf2f(pk.x & 0xffffu), f1 = bf2f(pk.x >> 16);
    float f2 = bf2f(pk.y & 0xffffu), f3 = bf2f(pk.y >> 16);
    float f4 = bf2f(pk.z & 0xffffu), f5 = bf2f(pk.z >> 16);
    float f6 = bf2f(pk.w & 0xffffu), f7 = bf2f(pk.w >> 16);
    float s = f0*f0 + f1*f1 + f2*f2 + f3*f3 + f4*f4 + f5*f5 + f6*f6 + f7*f7;
    s += __shfl_xor(s, 1);
    s += __shfl_xor(s, 2);
    s += __shfl_xor(s, 4);
    s += __shfl_xor(s, 8);
    if (seg == 0) inv[row] = 1.0f / sqrtf(fmaxf(s, 1e-16f));
}

// ---------------- main (fast path): single K=128 phase ----------------
// Tile 64 (N) x 128 (M); 4 waves; wave owns 16 rows x 128 cols (acc = 32 AGPR).
// B tile [128][128] bf16 (32 KB) staged in ONE round of global_load_lds with
// the XOR-swizzle folded into the global SOURCE address (linear LDS dest);
// z prefetched BEFORE staging (largest HBM read, consumed last).
// Barriers: 2 (vs 4 in R7) -> one HBM-latency drain instead of two.
__global__ __launch_bounds__(256, 5) void cossim_bce_fast(
    const int*  __restrict__ zp,
    const unsigned short* __restrict__ xb,
    const float* __restrict__ inv,
    const float* __restrict__ tparm,
    const float* __restrict__ bparm,
    float* __restrict__ out,
    float* __restrict__ cells)
{
    __shared__ __align__(16) unsigned short lB[128*128];   // 32 KB

    const int t  = threadIdx.x;
    const int bx = blockIdx.x;   // M tile (16)
    const int by = blockIdx.y;   // N tile (32)
    const int bz = blockIdx.z;   // batch

    const float tv = *tparm;
    const float bv = *bparm;

    const unsigned short* x1b = xb;                          // 16384 x 128
    const unsigned short* x2b = xb + (size_t)16384*128;      // 16384 x 128
    const int x1r0 = bz*NDIM + by*64;
    const int x2r0 = bz*MDIM + bx*128;

    const int lane = t & 63;
    const int w    = t >> 6;
    const int quad = lane >> 4;      // 0..3
    const int l16  = lane & 15;
    const int hi   = lane >> 5;      // 0..1
    const int c4   = lane & 31;

    f32x4 acc[8];
    #pragma unroll
    for (int n = 0; n < 8; ++n)
        acc[n] = (f32x4){0.f, 0.f, 0.f, 0.f};

    const size_t rowBase = (size_t)bz*NDIM*MDIM + (size_t)(by*64 + w*16)*MDIM + (size_t)(bx*128);

    // ---- z prefetch FIRST (needed last; ~900cy HBM latency hides under stage+MFMA) ----
    int4 zpre[4];
    #pragma unroll
    for (int i = 0; i < 4; ++i)
        zpre[i] = *(const int4*)(zp + rowBase + (size_t)(i*4 + hi)*MDIM + c4*4);

    // ---- stage ALL of B: 2048 16B-chunks; chunk = row*16+pp holds source
    //      pos pp^(row&7) -> consumer reads slot row*16+(kc^(row&7)) = B[row][kc] ----
    #pragma unroll
    for (int i = 0; i < 8; ++i){
        int chunk = i*256 + t;
        int row = chunk >> 4, pp = chunk & 15;
        int srcpos = pp ^ (row & 7);
        gload_lds16(x2b + ((size_t)(x2r0 + row))*128 + srcpos*8,
                    lB + (size_t)(i*256 + w*64)*8);
    }
    __syncthreads();

    // ---- MFMA: 4 k-steps of 32, A direct from global (L3-hot bf16) ----
    const unsigned short* aRow = x1b + ((size_t)(x1r0 + w*16 + l16))*128 + quad*8;
    #pragma unroll
    for (int kk = 0; kk < 4; ++kk){
        bf16x8 afr = *(const bf16x8*)(aRow + kk*32);
        const int kc = kk*4 + quad;              // 16B k-chunk 0..15
        #pragma unroll
        for (int g = 0; g < 2; ++g){
            bf16x8 bfr[4];
            #pragma unroll
            for (int nn = 0; nn < 4; ++nn){
                int brow = (g*4 + nn)*16 + l16;
                bfr[nn] = ((const bf16x8*)lB)[brow*16 + (kc ^ (brow & 7))];
            }
            #pragma unroll
            for (int nn = 0; nn < 4; ++nn)
                acc[g*4+nn] = __builtin_amdgcn_mfma_f32_16x16x32_bf16(
                                afr, bfr[nn], acc[g*4+nn], 0, 0, 0);
        }
    }

    // norms loaded after MFMA (L2/L3-hot; keeps MFMA-window reg pressure low)
    float in1[4], in2[8];
    #pragma unroll
    for (int r = 0; r < 4; ++r) in1[r] = inv[x1r0 + w*16 + quad*4 + r];
    #pragma unroll
    for (int n = 0; n < 8; ++n) in2[n] = inv[16384 + x2r0 + n*16 + l16];

    __syncthreads();   // B reads done -> per-wave scratch reuse

    // ---- barrier-free epilogue: per-wave 8x128 transpose scratch, 2 rounds ----
    float* scr = (float*)lB + w*1024;        // [8][128] f32, col-rotated by sr*4
    float* cosOut  = out + 1;
    float* maskOut = out + 1 + (size_t)BATCH*NDIM*MDIM;

    float lnum = 0.f;
    int   lcnt = 0;

    #pragma unroll
    for (int rr = 0; rr < 2; ++rr){
        // scatter: rows quad*4 + rr*2 + j -> scr row sr = quad*2+j
        #pragma unroll
        for (int n = 0; n < 8; ++n){
            #pragma unroll
            for (int j = 0; j < 2; ++j){
                int r  = rr*2 + j;
                int sr = quad*2 + j;
                scr[sr*128 + ((n*16 + l16 + sr*4) & 127)] = acc[n][r] * in1[r] * in2[n];
            }
        }
        // gather + math + streaming stores (wave-local LDS dep -> lgkmcnt only)
        #pragma unroll
        for (int i = 0; i < 4; ++i){
            int sr  = i*2 + hi;
            int col = (c4*4 + sr*4) & 127;
            f32x4 cs4 = *(const f32x4*)(scr + sr*128 + col);
            int rowRel = i*4 + rr*2 + hi;
            size_t idx = rowBase + (size_t)rowRel*MDIM + c4*4;

            int4 z4 = zpre[i];
            if (rr == 0)   // issue round-1 z load now (rows +2)
                zpre[i] = *(const int4*)(zp + idx + (size_t)2*MDIM);

            f32x4 mk;
            float nl = 0.f;
            int   nc = 0;
            #pragma unroll
            for (int j = 0; j < 4; ++j){
                int zv = (&z4.x)[j];
                float cs = cs4[j];
                mk[j] = zv ? 1.0f : 0.0f;
                float y  = (float)zv * (tv*cs - bv);
                float nll = fmaxf(-y, 0.f) + __logf(1.0f + __expf(-fabsf(y)));
                nl += zv ? nll : 0.f;
                nc += zv ? 1 : 0;
            }
            lnum += nl;
            lcnt += nc;
            *(f32x4u*)(cosOut  + idx) = cs4;
            *(f32x4u*)(maskOut + idx) = mk;
        }
    }

    // ---- block-level loss reduction: 1 atomic pair per block ----
    #pragma unroll
    for (int off = 32; off > 0; off >>= 1){
        lnum += __shfl_down(lnum, off);
        lcnt += __shfl_down(lcnt, off);
    }
    __syncthreads();                 // scratch reads done; reuse for reduce
    float* redf = (float*)lB;
    int*   redi = (int*)lB + 8;
    if (lane == 0){ redf[w] = lnum; redi[w] = lcnt; }
    __syncthreads();
    if (t == 0){
        float s = redf[0] + redf[1] + redf[2] + redf[3];
        int   c = redi[0] + redi[1] + redi[2] + redi[3];
        int cell = (bx + by*16 + bz*512) & 31;
        atomicAdd(cells + cell, s);
        atomicAdd((int*)cells + 32 + cell, c);
    }
}

// ---------------- fallback (proven R6 kernel, used if ws too small) ----------------
__global__ void ws_init_kernel(unsigned int* cells){
    cells[threadIdx.x] = 0u;
}

__global__ __launch_bounds__(256, 5) void cossim_bce_main(
    const int*  __restrict__ zp,
    const float* __restrict__ x1,
    const float* __restrict__ x2,
    const float* __restrict__ tparm,
    const float* __restrict__ bparm,
    float* __restrict__ out,
    float* __restrict__ wsf)
{
    __shared__ __align__(16) unsigned short lds[(64 + 128) * 64];
    __shared__ float nsh[192];
    unsigned short* lA = lds;
    unsigned short* lB = lds + 64*64;

    const int t  = threadIdx.x;
    const int bx = blockIdx.x;
    const int by = blockIdx.y;
    const int bz = blockIdx.z;

    const float tv = *tparm;
    const float bv = *bparm;

    const float* x1base = x1 + ((size_t)(bz*NDIM) + by*64 ) * CDIM;
    const float* x2base = x2 + ((size_t)(bz*MDIM) + bx*128) * CDIM;

    const int lane = t & 63;
    const int w    = t >> 6;
    const int quad = lane >> 4;
    const int l16  = lane & 15;
    const int hi   = lane >> 5;
    const int c4   = lane & 31;

    f32x4 acc[8];
    #pragma unroll
    for (int n = 0; n < 8; ++n)
        acc[n] = (f32x4){0.f, 0.f, 0.f, 0.f};

    float nsum = 0.f;

    #pragma unroll
    for (int ph = 0; ph < 2; ++ph){
        #pragma unroll
        for (int i = 0; i < 6; ++i){
            int chunk = i*256 + t;
            const float* srcb;
            uint4* dst;
            int row, pos;
            if (i < 2){
                row = chunk >> 3; pos = chunk & 7;
                srcb = x1base; dst = (uint4*)lA;
            } else {
                int c2 = chunk - 512;
                row = c2 >> 3; pos = c2 & 7;
                srcb = x2base; dst = (uint4*)lB;
            }
            const float* p = srcb + row*CDIM + ph*64 + pos*8;
            float4 a = *(const float4*)p;
            float4 b = *(const float4*)(p + 4);
            uint4 pk;
            pk.x = f2bf(a.x) | (f2bf(a.y) << 16);
            pk.y = f2bf(a.z) | (f2bf(a.w) << 16);
            pk.z = f2bf(b.x) | (f2bf(b.y) << 16);
            pk.w = f2bf(b.z) | (f2bf(b.w) << 16);
            dst[row*8 + (pos ^ (row & 7))] = pk;
        }
        __syncthreads();

        #pragma unroll
        for (int kk = 0; kk < 2; ++kk){
            const int kc = kk*4 + quad;
            const int arow = w*16 + l16;
            bf16x8 afr = ((const bf16x8*)lA)[arow*8 + (kc ^ (arow & 7))];
            #pragma unroll
            for (int g = 0; g < 2; ++g){
                bf16x8 bfr[4];
                #pragma unroll
                for (int nn = 0; nn < 4; ++nn){
                    int brow = (g*4 + nn)*16 + l16;
                    bfr[nn] = ((const bf16x8*)lB)[brow*8 + (kc ^ (brow & 7))];
                }
                #pragma unroll
                for (int nn = 0; nn < 4; ++nn)
                    acc[g*4+nn] = __builtin_amdgcn_mfma_f32_16x16x32_bf16(
                                    afr, bfr[nn], acc[g*4+nn], 0, 0, 0);
            }
        }

        if (t < 192){
            const uint4* base; int row;
            if (t < 64){ base = (const uint4*)lA; row = t; }
            else       { base = (const uint4*)lB; row = t - 64; }
            #pragma unroll
            for (int c = 0; c < 8; ++c){
                uint4 v = base[row*8 + (c ^ (row & 7))];
                float f0 = bf2f(v.x & 0xffffu), f1 = bf2f(v.x >> 16);
                float f2 = bf2f(v.y & 0xffffu), f3 = bf2f(v.y >> 16);
                float f4 = bf2f(v.z & 0xffffu), f5 = bf2f(v.z >> 16);
                float f6 = bf2f(v.w & 0xffffu), f7 = bf2f(v.w >> 16);
                nsum += f0*f0 + f1*f1 + f2*f2 + f3*f3 + f4*f4 + f5*f5 + f6*f6 + f7*f7;
            }
        }
        __syncthreads();
    }

    if (t < 192) nsh[t] = 1.0f / sqrtf(fmaxf(nsum, 1e-16f));
    __syncthreads();

    float in1[4], in2[8];
    #pragma unroll
    for (int r = 0; r < 4; ++r) in1[r] = nsh[w*16 + quad*4 + r];
    #pragma unroll
    for (int n = 0; n < 8; ++n) in2[n] = nsh[64 + n*16 + l16];

    float* scr = (float*)lds + w*1024;
    float* cosOut  = out + 1;
    float* maskOut = out + 1 + (size_t)BATCH*NDIM*MDIM;
    const size_t rowBase = (size_t)bz*NDIM*MDIM + (size_t)(by*64 + w*16)*MDIM + (size_t)(bx*128);

    float lnum = 0.f;
    int   lcnt = 0;

    int4 zpre[4];
    #pragma unroll
    for (int i = 0; i < 4; ++i)
        zpre[i] = *(const int4*)(zp + rowBase + (size_t)(i*4 + hi)*MDIM + c4*4);

    #pragma unroll
    for (int rr = 0; rr < 2; ++rr){
        #pragma unroll
        for (int n = 0; n < 8; ++n){
            #pragma unroll
            for (int j = 0; j < 2; ++j){
                int r  = rr*2 + j;
                int sr = quad*2 + j;
                scr[sr*128 + ((n*16 + l16 + sr*4) & 127)] = acc[n][r] * in1[r] * in2[n];
            }
        }
        #pragma unroll
        for (int i = 0; i < 4; ++i){
            int sr  = i*2 + hi;
            int col = (c4*4 + sr*4) & 127;
            f32x4 cs4 = *(const f32x4*)(scr + sr*128 + col);
            int rowRel = i*4 + rr*2 + hi;
            size_t idx = rowBase + (size_t)rowRel*MDIM + c4*4;

            int4 z4 = zpre[i];
            if (rr == 0)
                zpre[i] = *(const int4*)(zp + idx + (size_t)2*MDIM);

            f32x4 mk;
            float nl = 0.f;
            int   nc = 0;
            #pragma unroll
            for (int j = 0; j < 4; ++j){
                int zv = (&z4.x)[j];
                float cs = cs4[j];
                mk[j] = zv ? 1.0f : 0.0f;
                float y  = (float)zv * (tv*cs - bv);
                float nll = fmaxf(-y, 0.f) + __logf(1.0f + __expf(-fabsf(y)));
                nl += zv ? nll : 0.f;
                nc += zv ? 1 : 0;
            }
            lnum += nl;
            lcnt += nc;
            *(f32x4u*)(cosOut  + idx) = cs4;
            *(f32x4u*)(maskOut + idx) = mk;
        }
    }

    #pragma unroll
    for (int off = 32; off > 0; off >>= 1){
        lnum += __shfl_down(lnum, off);
        lcnt += __shfl_down(lcnt, off);
    }
    __syncthreads();
    if (lane == 0){ nsh[w] = lnum; ((int*)nsh)[4 + w] = lcnt; }
    __syncthreads();
    if (t == 0){
        float s = nsh[0] + nsh[1] + nsh[2] + nsh[3];
        int   c = ((int*)nsh)[4] + ((int*)nsh)[5] + ((int*)nsh)[6] + ((int*)nsh)[7];
        int cell = (bx + by*16 + bz*512) & 31;
        atomicAdd(wsf + cell, s);
        atomicAdd((int*)wsf + 32 + cell, c);
    }
}

extern "C" void kernel_launch(void* const* d_in, const int* in_sizes, int n_in,
                              void* d_out, int out_size, void* d_ws, size_t ws_size,
                              hipStream_t stream) {
    const int*   zp = (const int*)  d_in[0];
    const float* x1 = (const float*)d_in[1];
    const float* x2 = (const float*)d_in[2];
    const float* tp = (const float*)d_in[3];
    const float* bp = (const float*)d_in[4];
    float* out = (float*)d_out;

    // ws fast-path layout: xb bf16[32768*128] (8 MB) | inv f32[32768] (128 KB) | cells (256 B)
    const size_t WS_NEEDED = (size_t)8*1024*1024 + 32768*4 + 256;
    dim3 grid(MDIM/128, NDIM/64, BATCH);

    if (ws_size >= WS_NEEDED){
        unsigned short* xb  = (unsigned short*)d_ws;
        float* inv   = (float*)((char*)d_ws + (size_t)8*1024*1024);
        float* cells = inv + 32768;
        prep_kernel<<<2048, 256, 0, stream>>>(x1, x2, xb, inv, (unsigned int*)cells);
        cossim_bce_fast<<<grid, 256, 0, stream>>>(zp, xb, inv, tp, bp, out, cells);
        finalize_kernel<<<1, 1, 0, stream>>>(cells, out);
    } else {
        float* wsf = (float*)d_ws;
        ws_init_kernel<<<1, 64, 0, stream>>>((unsigned int*)d_ws);
        cossim_bce_main<<<grid, 256, 0, stream>>>(zp, x1, x2, tp, bp, out, wsf);
        finalize_kernel<<<1, 1, 0, stream>>>(wsf, out);
    }
}